// Round 1
// baseline (384.074 us; speedup 1.0000x reference)
//
#include <hip/hip_runtime.h>

// PhotometricLoss: fused warp + SSIM(3x3 avgpool, zero-pad) + L1 + masked mean.
// B=8, C=3, H=720, W=1280 fp32. Memory-bound: ~206MB unique input -> ~33us floor.
//
// One block = 32x32 output tile, 256 threads (32 cols x 8 row-groups, each
// thread owns 4 adjacent rows). Per channel: stage left + warped(right,disp)
// into LDS with 1-px halo (zero outside image == reference zero padding),
// sliding 3-wide row sums of {x,y,xx,yy,xy}, SSIM + L1 at center.

#define P_ALPHA 0.85f
#define P_C1 1e-4f
#define P_C2 9e-4f

constexpr int TW = 32;           // tile width (output)
constexpr int TH = 32;           // tile height (output)
constexpr int LW = TW + 2;       // 34: tile + halo
constexpr int LH = TH + 2;       // 34
constexpr int LSTR = 34;         // LDS row stride (floats)

__global__ __launch_bounds__(256)
void photo_loss_kernel(const float* __restrict__ disp,
                       const float* __restrict__ left,
                       const float* __restrict__ right,
                       float* __restrict__ acc,   // acc[0]=sum(photo*valid), acc[1]=sum(valid)
                       int B, int H, int W)
{
    __shared__ float Xs[LH * LSTR];
    __shared__ float Ys[LH * LSTR];
    __shared__ float redpv[4];
    __shared__ float redv[4];

    const int tid   = threadIdx.x;
    const int tx    = tid & 31;        // column within tile
    const int ty    = tid >> 5;        // row group 0..7 (each owns 4 rows)
    const int tileX = blockIdx.x * TW;
    const int tileY = blockIdx.y * TH;
    const int b     = blockIdx.z;

    const int planeHW = H * W;
    const float* dispb = disp + b * planeHW;
    const float wm1f = (float)(W - 1);

    float ssim_acc[4] = {0.f, 0.f, 0.f, 0.f};
    float l1_acc[4]   = {0.f, 0.f, 0.f, 0.f};

    for (int c = 0; c < 3; ++c) {
        const float* leftc  = left  + ((b * 3 + c) * planeHW);
        const float* rightc = right + ((b * 3 + c) * planeHW);

        // ---- stage tile + halo: x = left, y = warped(right, disp) ----
        for (int e = tid; e < LH * LW; e += 256) {
            int ly = e / LW;
            int lc = e - ly * LW;
            int gh = tileY - 1 + ly;
            int gw = tileX - 1 + lc;
            float xv = 0.f, yv = 0.f;
            if (gh >= 0 && gh < H && gw >= 0 && gw < W) {
                int rowoff = gh * W;
                xv = leftc[rowoff + gw];
                float d  = dispb[rowoff + gw];
                float xs = (float)gw - d;                 // x_sample
                xs = fminf(fmaxf(xs, 0.f), wm1f);         // border clamp
                float x0 = floorf(xs);
                float fr = xs - x0;                       // frac weight
                int i0 = (int)x0;
                int i1 = min(i0 + 1, W - 1);
                float g0 = rightc[rowoff + i0];
                float g1 = rightc[rowoff + i1];
                yv = (1.f - fr) * g0 + fr * g1;           // match reference formula
            }
            Xs[ly * LSTR + lc] = xv;
            Ys[ly * LSTR + lc] = yv;
        }
        __syncthreads();

        // ---- sliding 3-wide row sums over the 6 input rows this thread needs ----
        const int lx = tx + 1;
        float rsx[6], rsy[6], rsxx[6], rsyy[6], rsxy[6];
        #pragma unroll
        for (int j = 0; j < 6; ++j) {
            int ly = ty * 4 + j;       // LDS row (halo-offset): covers out rows ty*4-1 .. ty*4+4
            const float* xr = &Xs[ly * LSTR + lx - 1];
            const float* yr = &Ys[ly * LSTR + lx - 1];
            float x0 = xr[0], x1 = xr[1], x2 = xr[2];
            float y0 = yr[0], y1 = yr[1], y2 = yr[2];
            rsx[j]  = x0 + x1 + x2;
            rsy[j]  = y0 + y1 + y2;
            rsxx[j] = x0 * x0 + x1 * x1 + x2 * x2;
            rsyy[j] = y0 * y0 + y1 * y1 + y2 * y2;
            rsxy[j] = x0 * y0 + x1 * y1 + x2 * y2;
        }

        const float inv9 = 1.f / 9.f;
        #pragma unroll
        for (int r = 0; r < 4; ++r) {
            float mu_x = (rsx[r]  + rsx[r + 1]  + rsx[r + 2])  * inv9;
            float mu_y = (rsy[r]  + rsy[r + 1]  + rsy[r + 2])  * inv9;
            float exx  = (rsxx[r] + rsxx[r + 1] + rsxx[r + 2]) * inv9;
            float eyy  = (rsyy[r] + rsyy[r + 1] + rsyy[r + 2]) * inv9;
            float exy  = (rsxy[r] + rsxy[r + 1] + rsxy[r + 2]) * inv9;
            float sig_x  = fmaxf(exx - mu_x * mu_x, 0.f);
            float sig_y  = fmaxf(eyy - mu_y * mu_y, 0.f);
            float sig_xy = exy - mu_x * mu_y;
            float n  = (2.f * mu_x * mu_y + P_C1) * (2.f * sig_xy + P_C2);
            float dd = (mu_x * mu_x + mu_y * mu_y + P_C1) * (sig_x + sig_y + P_C2);
            float s  = (1.f - n / dd) * 0.5f;
            s = fminf(fmaxf(s, 0.f), 1.f);
            ssim_acc[r] += s;
            float cx = Xs[(ty * 4 + r + 1) * LSTR + lx];
            float cy = Ys[(ty * 4 + r + 1) * LSTR + lx];
            l1_acc[r] += fabsf(cx - cy);
        }
        __syncthreads();   // before next channel overwrites LDS
    }

    // ---- per-pixel finalize: valid mask + photo error ----
    float sum_pv = 0.f, sum_v = 0.f;
    const int gw = tileX + tx;
    #pragma unroll
    for (int r = 0; r < 4; ++r) {
        int gh = tileY + ty * 4 + r;
        if (gh < H && gw < W) {
            float d  = dispb[gh * W + gw];
            float xs = (float)gw - d;                     // unclamped x_sample
            float valid = (xs > 0.f && xs < wm1f) ? 1.f : 0.f;
            float photo = P_ALPHA * (ssim_acc[r] * (1.f / 3.f))
                        + (1.f - P_ALPHA) * (l1_acc[r] * (1.f / 3.f));
            sum_pv += photo * valid;
            sum_v  += valid;
        }
    }

    // ---- block reduction: wave shuffle (64 lanes) then LDS across 4 waves ----
    #pragma unroll
    for (int off = 32; off > 0; off >>= 1) {
        sum_pv += __shfl_down(sum_pv, off, 64);
        sum_v  += __shfl_down(sum_v,  off, 64);
    }
    int wid  = tid >> 6;
    int lane = tid & 63;
    if (lane == 0) { redpv[wid] = sum_pv; redv[wid] = sum_v; }
    __syncthreads();
    if (tid == 0) {
        float pv = redpv[0] + redpv[1] + redpv[2] + redpv[3];
        float v  = redv[0]  + redv[1]  + redv[2]  + redv[3];
        atomicAdd(&acc[0], pv);
        atomicAdd(&acc[1], v);
    }
}

__global__ void photo_loss_finalize(const float* __restrict__ acc,
                                    float* __restrict__ out)
{
    out[0] = acc[0] / fmaxf(acc[1], 1.f);
}

extern "C" void kernel_launch(void* const* d_in, const int* in_sizes, int n_in,
                              void* d_out, int out_size, void* d_ws, size_t ws_size,
                              hipStream_t stream)
{
    const float* disp  = (const float*)d_in[0];
    const float* left  = (const float*)d_in[1];
    const float* right = (const float*)d_in[2];
    float* out = (float*)d_out;
    float* acc = (float*)d_ws;

    const int B = 8, H = 720, W = 1280;
    // (sanity: in_sizes[0] == B*1*H*W, in_sizes[1] == B*3*H*W)

    hipMemsetAsync(acc, 0, 2 * sizeof(float), stream);

    dim3 grid((W + TW - 1) / TW, (H + TH - 1) / TH, B);   // 40 x 23 x 8
    dim3 block(256);
    photo_loss_kernel<<<grid, block, 0, stream>>>(disp, left, right, acc, B, H, W);
    photo_loss_finalize<<<1, 1, 0, stream>>>(acc, out);
}

// Round 2
// 263.743 us; speedup vs baseline: 1.4562x; 1.4562x over previous
//
#include <hip/hip_runtime.h>

// PhotometricLoss: fused warp + SSIM(3x3 avgpool, zero-pad) + L1 + masked mean.
// B=8, C=3, H=720, W=1280 fp32.
//
// R2 design: wave-streaming, no LDS tiles, no barriers in the hot path.
// Each wave owns a 64-lane column strip (lanes 0 and 63 are halo, 62 useful
// output columns) and streams down 18 output rows (+2 halo rows). Per row:
// load disp once, left x3, bilinear-gather right x3; horizontal 3-sums via
// __shfl(+-1); 3-row register ring of row-sums {x,y,xx,yy,xy} per channel
// (slots cycle statically mod 3 -> pure registers, no moves). L1 |x-y| and
// the valid mask are folded into per-row ring scalars at load time.

#define P_ALPHA 0.85f
#define P_C1 1e-4f
#define P_C2 9e-4f

constexpr int COLS = 62;   // useful output columns per wave strip
constexpr int RPW  = 18;   // output rows per wave (multiple of 3)
constexpr int WAVES = 4;   // waves per block

__global__ __launch_bounds__(256)
void photo_loss_kernel(const float* __restrict__ disp,
                       const float* __restrict__ left,
                       const float* __restrict__ right,
                       float* __restrict__ acc,   // acc[0]=sum(photo*valid), acc[1]=sum(valid)
                       int H, int W)
{
    __shared__ float redpv[WAVES];
    __shared__ float redv[WAVES];

    const int tid  = threadIdx.x;
    const int lane = tid & 63;
    const int w    = tid >> 6;
    const int b    = blockIdx.z;
    const int col  = blockIdx.x * COLS + lane - 1;          // -1 .. W+halo
    const int rowStart = (blockIdx.y * WAVES + w) * RPW;

    const int planeHW = H * W;
    const float* __restrict__ dispb = disp  + b * planeHW;
    const float* __restrict__ L0 = left  + (b * 3 + 0) * planeHW;
    const float* __restrict__ L1 = left  + (b * 3 + 1) * planeHW;
    const float* __restrict__ L2 = left  + (b * 3 + 2) * planeHW;
    const float* __restrict__ R0 = right + (b * 3 + 0) * planeHW;
    const float* __restrict__ R1 = right + (b * 3 + 1) * planeHW;
    const float* __restrict__ R2 = right + (b * 3 + 2) * planeHW;

    const float wm1f = (float)(W - 1);
    const bool col_in  = (col >= 0) && (col < W);
    const bool out_col = (lane >= 1) && (lane <= COLS) && (col < W);  // col>=0 implied

    // 3-row register rings (slot indices are always compile-time constants)
    float rsx[3][3], rsy[3][3], rsxx[3][3], rsyy[3][3], rsxy[3][3];
    float l1r[3], vr[3];

    float sum_pv = 0.f, sum_v = 0.f;

    // load row r, compute horizontal 3-sums into ring slot s
    auto step_load = [&](int r, int s) {
        float x0 = 0.f, x1 = 0.f, x2 = 0.f;
        float y0 = 0.f, y1 = 0.f, y2 = 0.f;
        float valid = 0.f;
        if (col_in && (unsigned)r < (unsigned)H) {
            const int off = r * W + col;
            const float d = dispb[off];
            x0 = L0[off]; x1 = L1[off]; x2 = L2[off];
            const float xs = (float)col - d;                    // x_sample (unclamped)
            valid = (xs > 0.f && xs < wm1f) ? 1.f : 0.f;
            float xc = fminf(fmaxf(xs, 0.f), wm1f);             // border clamp
            float xf = floorf(xc);
            float fr = xc - xf;
            int i0 = (int)xf;
            int i1 = min(i0 + 1, W - 1);
            const int ro = r * W;
            float g00 = R0[ro + i0], g01 = R0[ro + i1];
            float g10 = R1[ro + i0], g11 = R1[ro + i1];
            float g20 = R2[ro + i0], g21 = R2[ro + i1];
            const float omf = 1.f - fr;
            y0 = omf * g00 + fr * g01;
            y1 = omf * g10 + fr * g11;
            y2 = omf * g20 + fr * g21;
        }
        // horizontal neighbors via shuffle (halo lanes 0/63 feed lanes 1/62)
        float xl, xr, yl, yr;
        xl = __shfl_up(x0, 1, 64); xr = __shfl_down(x0, 1, 64);
        yl = __shfl_up(y0, 1, 64); yr = __shfl_down(y0, 1, 64);
        rsx[0][s]  = xl + x0 + xr;
        rsy[0][s]  = yl + y0 + yr;
        rsxx[0][s] = xl * xl + x0 * x0 + xr * xr;
        rsyy[0][s] = yl * yl + y0 * y0 + yr * yr;
        rsxy[0][s] = xl * yl + x0 * y0 + xr * yr;

        xl = __shfl_up(x1, 1, 64); xr = __shfl_down(x1, 1, 64);
        yl = __shfl_up(y1, 1, 64); yr = __shfl_down(y1, 1, 64);
        rsx[1][s]  = xl + x1 + xr;
        rsy[1][s]  = yl + y1 + yr;
        rsxx[1][s] = xl * xl + x1 * x1 + xr * xr;
        rsyy[1][s] = yl * yl + y1 * y1 + yr * yr;
        rsxy[1][s] = xl * yl + x1 * y1 + xr * yr;

        xl = __shfl_up(x2, 1, 64); xr = __shfl_down(x2, 1, 64);
        yl = __shfl_up(y2, 1, 64); yr = __shfl_down(y2, 1, 64);
        rsx[2][s]  = xl + x2 + xr;
        rsy[2][s]  = yl + y2 + yr;
        rsxx[2][s] = xl * xl + x2 * x2 + xr * xr;
        rsyy[2][s] = yl * yl + y2 * y2 + yr * yr;
        rsxy[2][s] = xl * yl + x2 * y2 + xr * yr;

        l1r[s] = fabsf(x0 - y0) + fabsf(x1 - y1) + fabsf(x2 - y2);
        vr[s]  = valid;
    };

    // emit output for the row whose raw values live in ring slot cs
    auto emit = [&](int cs) {
        float ssim_sum = 0.f;
        #pragma unroll
        for (int c = 0; c < 3; ++c) {
            const float inv9 = 1.f / 9.f;
            float mu_x = (rsx[c][0]  + rsx[c][1]  + rsx[c][2])  * inv9;
            float mu_y = (rsy[c][0]  + rsy[c][1]  + rsy[c][2])  * inv9;
            float exx  = (rsxx[c][0] + rsxx[c][1] + rsxx[c][2]) * inv9;
            float eyy  = (rsyy[c][0] + rsyy[c][1] + rsyy[c][2]) * inv9;
            float exy  = (rsxy[c][0] + rsxy[c][1] + rsxy[c][2]) * inv9;
            float sig_x  = fmaxf(exx - mu_x * mu_x, 0.f);
            float sig_y  = fmaxf(eyy - mu_y * mu_y, 0.f);
            float sig_xy = exy - mu_x * mu_y;
            float n  = (2.f * mu_x * mu_y + P_C1) * (2.f * sig_xy + P_C2);
            float dd = (mu_x * mu_x + mu_y * mu_y + P_C1) * (sig_x + sig_y + P_C2);
            float s  = (1.f - n * __builtin_amdgcn_rcpf(dd)) * 0.5f;  // dd >= C1*C2 > 0
            s = fminf(fmaxf(s, 0.f), 1.f);
            ssim_sum += s;
        }
        float photo = P_ALPHA * (ssim_sum * (1.f / 3.f))
                    + (1.f - P_ALPHA) * (l1r[cs] * (1.f / 3.f));
        if (out_col) {
            sum_pv += photo * vr[cs];
            sum_v  += vr[cs];
        }
    };

    // prologue: rows rowStart-1, rowStart into slots 0,1
    step_load(rowStart - 1, 0);
    step_load(rowStart,     1);

    int r = rowStart + 1;
    for (int jo = 0; jo < RPW / 3; ++jo) {
        step_load(r,     2); emit(1);   // window r-2..r, center slot 1
        step_load(r + 1, 0); emit(2);
        step_load(r + 2, 1); emit(0);
        r += 3;
    }

    // wave reduce (64 lanes) then cross-wave via tiny LDS
    #pragma unroll
    for (int off = 32; off > 0; off >>= 1) {
        sum_pv += __shfl_down(sum_pv, off, 64);
        sum_v  += __shfl_down(sum_v,  off, 64);
    }
    if (lane == 0) { redpv[w] = sum_pv; redv[w] = sum_v; }
    __syncthreads();
    if (tid == 0) {
        atomicAdd(&acc[0], redpv[0] + redpv[1] + redpv[2] + redpv[3]);
        atomicAdd(&acc[1], redv[0]  + redv[1]  + redv[2]  + redv[3]);
    }
}

__global__ void photo_loss_finalize(const float* __restrict__ acc,
                                    float* __restrict__ out)
{
    out[0] = acc[0] / fmaxf(acc[1], 1.f);
}

extern "C" void kernel_launch(void* const* d_in, const int* in_sizes, int n_in,
                              void* d_out, int out_size, void* d_ws, size_t ws_size,
                              hipStream_t stream)
{
    const float* disp  = (const float*)d_in[0];
    const float* left  = (const float*)d_in[1];
    const float* right = (const float*)d_in[2];
    float* out = (float*)d_out;
    float* acc = (float*)d_ws;

    const int B = 8, H = 720, W = 1280;

    hipMemsetAsync(acc, 0, 2 * sizeof(float), stream);

    // x: 21 strips of 62 cols; y: 720 / (4 waves * 18 rows) = 10; z: batch
    dim3 grid((W + COLS - 1) / COLS, H / (WAVES * RPW), B);
    dim3 block(256);
    photo_loss_kernel<<<grid, block, 0, stream>>>(disp, left, right, acc, H, W);
    photo_loss_finalize<<<1, 1, 0, stream>>>(acc, out);
}

// Round 3
// 242.161 us; speedup vs baseline: 1.5860x; 1.0891x over previous
//
#include <hip/hip_runtime.h>

// PhotometricLoss: fused warp + SSIM(3x3 avgpool, zero-pad) + L1 + masked mean.
// B=8, C=3, H=720, W=1280 fp32.
//
// R3: branchless wave-streaming with explicit software pipeline.
// Each wave owns a 64-lane column strip (lanes 0/63 halo, 62 useful cols) and
// streams 12 output rows (+2 halo). Pipeline: disp/left for row r+1 prefetch
// at step r (removes disp from the gather dependent chain); right-gather loads
// for row r issue at step start; SSIM emit for center r-2 (pure VALU) fills
// the gather shadow. All edge handling via clamped addresses + 0/1 mask
// multiplies -> zero divergent branches in the hot loop, loads hoistable.

#define P_ALPHA 0.85f
#define P_C1 1e-4f
#define P_C2 9e-4f

constexpr int COLS  = 62;   // useful output columns per wave strip
constexpr int RPW   = 12;   // output rows per wave (720 = 15*4*12)
constexpr int WAVES = 4;    // waves per block

__global__ __launch_bounds__(256)
void photo_loss_kernel(const float* __restrict__ disp,
                       const float* __restrict__ left,
                       const float* __restrict__ right,
                       float* __restrict__ acc,   // acc[0]=sum(photo*valid), acc[1]=sum(valid)
                       int H, int W)
{
    __shared__ float redpv[WAVES];
    __shared__ float redv[WAVES];

    const int tid  = threadIdx.x;
    const int lane = tid & 63;
    const int w    = tid >> 6;
    const int b    = blockIdx.z;
    const int col  = blockIdx.x * COLS + lane - 1;          // -1 .. W (+halo)
    const int rowStart = (blockIdx.y * WAVES + w) * RPW;

    const int planeHW = H * W;
    const float* __restrict__ dispb = disp  + b * planeHW;
    const float* __restrict__ L0 = left  + (b * 3 + 0) * planeHW;
    const float* __restrict__ L1 = left  + (b * 3 + 1) * planeHW;
    const float* __restrict__ L2 = left  + (b * 3 + 2) * planeHW;
    const float* __restrict__ R0 = right + (b * 3 + 0) * planeHW;
    const float* __restrict__ R1 = right + (b * 3 + 1) * planeHW;
    const float* __restrict__ R2 = right + (b * 3 + 2) * planeHW;

    const float wm1f = (float)(W - 1);
    const int   colC = min(max(col, 0), W - 1);             // clamped address col
    const float colv = (col >= 0 && col < W) ? 1.f : 0.f;   // column validity
    const float ocm  = (lane >= 1 && lane <= COLS && col < W) ? 1.f : 0.f;  // output mask

    // 3-row register rings (all indices compile-time after full unroll)
    float rsx[3][3], rsy[3][3], rsxx[3][3], rsyy[3][3], rsxy[3][3];
    float l1r[3], vr[3];

    float sum_pv = 0.f, sum_v = 0.f;

    // emit center row held in ring slot cs (sums over all 3 slots, order-free)
    auto emit = [&](int cs) {
        const float inv9 = 1.f / 9.f;
        float ssim_sum = 0.f;
        #pragma unroll
        for (int c = 0; c < 3; ++c) {
            float mu_x = (rsx[c][0]  + rsx[c][1]  + rsx[c][2])  * inv9;
            float mu_y = (rsy[c][0]  + rsy[c][1]  + rsy[c][2])  * inv9;
            float exx  = (rsxx[c][0] + rsxx[c][1] + rsxx[c][2]) * inv9;
            float eyy  = (rsyy[c][0] + rsyy[c][1] + rsyy[c][2]) * inv9;
            float exy  = (rsxy[c][0] + rsxy[c][1] + rsxy[c][2]) * inv9;
            float sig_x  = fmaxf(exx - mu_x * mu_x, 0.f);
            float sig_y  = fmaxf(eyy - mu_y * mu_y, 0.f);
            float sig_xy = exy - mu_x * mu_y;
            float n  = (2.f * mu_x * mu_y + P_C1) * (2.f * sig_xy + P_C2);
            float dd = (mu_x * mu_x + mu_y * mu_y + P_C1) * (sig_x + sig_y + P_C2);
            float s  = (1.f - n * __builtin_amdgcn_rcpf(dd)) * 0.5f;  // dd >= C1*C2 > 0
            s = fminf(fmaxf(s, 0.f), 1.f);
            ssim_sum += s;
        }
        float photo = P_ALPHA * (ssim_sum * (1.f / 3.f))
                    + (1.f - P_ALPHA) * (l1r[cs] * (1.f / 3.f));
        sum_pv += photo * vr[cs] * ocm;
        sum_v  += vr[cs] * ocm;
    };

    // pipeline registers: disp/left of the row being gathered this step
    float dC, xC0, xC1, xC2;
    {
        const int r  = rowStart - 1;
        const int rc = min(max(r, 0), H - 1);
        const int off = rc * W + colC;
        dC = dispb[off]; xC0 = L0[off]; xC1 = L1[off]; xC2 = L2[off];
    }

    #pragma unroll
    for (int j = 0; j <= RPW + 2; ++j) {
        const int s = j % 3;                    // ring slot to write (compile-time)
        const int r = rowStart - 1 + j;         // row gathered this step
        if (j <= RPW + 1) {
            const int   rc = min(max(r, 0), H - 1);
            const float rv = (r >= 0 && r < H) ? 1.f : 0.f;
            const float m  = rv * colv;

            // ---- gather-issue for row r (dC arrived a full step ago) ----
            const float xs  = (float)col - dC;
            const float xcl = fminf(fmaxf(xs, 0.f), wm1f);
            const float xf  = floorf(xcl);
            const float fr  = xcl - xf;
            const int   i0  = (int)xf;
            const int   i1  = min(i0 + 1, W - 1);
            const int   ro  = rc * W;
            const float g00 = R0[ro + i0], g01 = R0[ro + i1];
            const float g10 = R1[ro + i0], g11 = R1[ro + i1];
            const float g20 = R2[ro + i0], g21 = R2[ro + i1];

            // ---- prefetch disp/left for row r+1 (independent loads) ----
            float dN = 0.f, xN0 = 0.f, xN1 = 0.f, xN2 = 0.f;
            if (j <= RPW) {
                const int rn   = min(max(r + 1, 0), H - 1);
                const int offn = rn * W + colC;
                dN = dispb[offn]; xN0 = L0[offn]; xN1 = L1[offn]; xN2 = L2[offn];
            }

            // ---- emit center r-2 in the gather shadow (ring slots intact) ----
            if (j >= 3) emit((s + 1) % 3);

            // ---- consume gathers: warp values, shuffles, ring slot s ----
            const float omf = 1.f - fr;
            const float y0 = (omf * g00 + fr * g01) * m;
            const float y1 = (omf * g10 + fr * g11) * m;
            const float y2 = (omf * g20 + fr * g21) * m;
            const float x0 = xC0 * m;
            const float x1 = xC1 * m;
            const float x2 = xC2 * m;

            float xl, xr, yl, yr;
            xl = __shfl_up(x0, 1, 64); xr = __shfl_down(x0, 1, 64);
            yl = __shfl_up(y0, 1, 64); yr = __shfl_down(y0, 1, 64);
            rsx[0][s]  = xl + x0 + xr;
            rsy[0][s]  = yl + y0 + yr;
            rsxx[0][s] = xl * xl + x0 * x0 + xr * xr;
            rsyy[0][s] = yl * yl + y0 * y0 + yr * yr;
            rsxy[0][s] = xl * yl + x0 * y0 + xr * yr;

            xl = __shfl_up(x1, 1, 64); xr = __shfl_down(x1, 1, 64);
            yl = __shfl_up(y1, 1, 64); yr = __shfl_down(y1, 1, 64);
            rsx[1][s]  = xl + x1 + xr;
            rsy[1][s]  = yl + y1 + yr;
            rsxx[1][s] = xl * xl + x1 * x1 + xr * xr;
            rsyy[1][s] = yl * yl + y1 * y1 + yr * yr;
            rsxy[1][s] = xl * yl + x1 * y1 + xr * yr;

            xl = __shfl_up(x2, 1, 64); xr = __shfl_down(x2, 1, 64);
            yl = __shfl_up(y2, 1, 64); yr = __shfl_down(y2, 1, 64);
            rsx[2][s]  = xl + x2 + xr;
            rsy[2][s]  = yl + y2 + yr;
            rsxx[2][s] = xl * xl + x2 * x2 + xr * xr;
            rsyy[2][s] = yl * yl + y2 * y2 + yr * yr;
            rsxy[2][s] = xl * yl + x2 * y2 + xr * yr;

            l1r[s] = fabsf(x0 - y0) + fabsf(x1 - y1) + fabsf(x2 - y2);
            vr[s]  = (xs > 0.f && xs < wm1f) ? 1.f : 0.f;

            // rotate pipeline
            dC = dN; xC0 = xN0; xC1 = xN1; xC2 = xN2;
        } else {
            emit((s + 1) % 3);                  // final center rowStart+RPW-1
        }
    }

    // wave reduce (64 lanes) then cross-wave via tiny LDS
    #pragma unroll
    for (int off = 32; off > 0; off >>= 1) {
        sum_pv += __shfl_down(sum_pv, off, 64);
        sum_v  += __shfl_down(sum_v,  off, 64);
    }
    if (lane == 0) { redpv[w] = sum_pv; redv[w] = sum_v; }
    __syncthreads();
    if (tid == 0) {
        atomicAdd(&acc[0], redpv[0] + redpv[1] + redpv[2] + redpv[3]);
        atomicAdd(&acc[1], redv[0]  + redv[1]  + redv[2]  + redv[3]);
    }
}

__global__ void photo_loss_finalize(const float* __restrict__ acc,
                                    float* __restrict__ out)
{
    out[0] = acc[0] / fmaxf(acc[1], 1.f);
}

extern "C" void kernel_launch(void* const* d_in, const int* in_sizes, int n_in,
                              void* d_out, int out_size, void* d_ws, size_t ws_size,
                              hipStream_t stream)
{
    const float* disp  = (const float*)d_in[0];
    const float* left  = (const float*)d_in[1];
    const float* right = (const float*)d_in[2];
    float* out = (float*)d_out;
    float* acc = (float*)d_ws;

    const int B = 8, H = 720, W = 1280;

    hipMemsetAsync(acc, 0, 2 * sizeof(float), stream);

    // x: 21 strips of 62 cols; y: 720 / (4 waves * 12 rows) = 15; z: batch
    dim3 grid((W + COLS - 1) / COLS, H / (WAVES * RPW), B);
    dim3 block(256);
    photo_loss_kernel<<<grid, block, 0, stream>>>(disp, left, right, acc, H, W);
    photo_loss_finalize<<<1, 1, 0, stream>>>(acc, out);
}